// Round 1
// baseline (147.852 us; speedup 1.0000x reference)
//
#include <hip/hip_runtime.h>
#include <hip/hip_bf16.h>
#include <math.h>

// TopicRouter, single fused kernel:
//  logits[B,8] = h @ gate_w^T + b, plus per-row top-2 + softmax, all in one pass.
//  HBM-bound (96 MB of h). Gate weights live in 96 VGPRs per lane
//  (loop-invariant, no LDS at all). One wave per row-pair, software-prefetch
//  depth 1 held in registers — __launch_bounds__(256,2) gives a 256-VGPR
//  budget so nothing spills (R2's (256,4) + LDS tile spilled the prefetch
//  buffer: +96 MB scratch writes to HBM).
//  Top-2 is computed in-register after the wave reduce: every 8-lane group
//  holds all 8 expert logits (one per lane), so a 3-step shfl_xor merge
//  network gives top-2 with lax.top_k tie semantics (strict >, lower index
//  wins ties). This eliminates the old router_topk kernel: one fewer
//  dispatch, no serialized 1 MB logits re-read.

constexpr int D  = 768;
constexpr int E  = 8;
constexpr int D4 = D / 4;          // 192 float4 per row
constexpr int BLOCK  = 256;        // 4 waves
constexpr int GRID_A = 512;        // 2048 waves -> 8 row-pairs per wave

__device__ __forceinline__ float dot4acc(float4 a, float4 b, float acc) {
    acc = fmaf(a.x, b.x, acc);
    acc = fmaf(a.y, b.y, acc);
    acc = fmaf(a.z, b.z, acc);
    acc = fmaf(a.w, b.w, acc);
    return acc;
}

// Reduce a[8] (per-expert partials) across 64 lanes.
// Returns: this lane's total for expert e = bitrev3(lane&7).
__device__ __forceinline__ float wave_reduce8(float a[8], int lane) {
    {   // xor 1: 8 -> 4 values
        const bool hi = lane & 1;
#pragma unroll
        for (int j = 0; j < 4; ++j) {
            float send = hi ? a[j] : a[j + 4];
            float recv = __shfl_xor(send, 1, 64);
            float keep = hi ? a[j + 4] : a[j];
            a[j] = keep + recv;
        }
    }
    {   // xor 2: 4 -> 2
        const bool hi = lane & 2;
#pragma unroll
        for (int j = 0; j < 2; ++j) {
            float send = hi ? a[j] : a[j + 2];
            float recv = __shfl_xor(send, 2, 64);
            float keep = hi ? a[j + 2] : a[j];
            a[j] = keep + recv;
        }
    }
    {   // xor 4: 2 -> 1
        const bool hi = lane & 4;
        float send = hi ? a[0] : a[1];
        float recv = __shfl_xor(send, 4, 64);
        float keep = hi ? a[1] : a[0];
        a[0] = keep + recv;
    }
    float v = a[0];
    v += __shfl_xor(v, 8, 64);
    v += __shfl_xor(v, 16, 64);
    v += __shfl_xor(v, 32, 64);
    return v;
}

__device__ __forceinline__ void load_pair(float4 dst[6], const float4* __restrict__ h4,
                                          int pair, int lane) {
    const float4* hp = h4 + (size_t)pair * (2 * D4) + lane;
#pragma unroll
    for (int c = 0; c < 3; ++c) dst[c]     = hp[c * 64];        // row 2p
#pragma unroll
    for (int c = 0; c < 3; ++c) dst[3 + c] = hp[D4 + c * 64];   // row 2p+1
}

__global__ __launch_bounds__(BLOCK, 2)
void router_fused_kernel(const float* __restrict__ h,
                         const float* __restrict__ gate_w,
                         const float* __restrict__ gate_b,
                         float* __restrict__ out_idx,
                         float* __restrict__ out_w,
                         float* __restrict__ out_logits,
                         int B) {
    const int tid    = threadIdx.x;
    const int lane   = tid & 63;
    const int wave   = tid >> 6;
    const int gwave  = blockIdx.x * (BLOCK / 64) + wave;
    const int nwaves = gridDim.x * (BLOCK / 64);

    const int l3 = lane & 7;
    const int e_lane = ((l3 & 1) << 2) | (l3 & 2) | ((l3 >> 2) & 1);  // bitrev3
    const float bias = gate_b[e_lane];

    // Loop-invariant gate slice for this lane: 24 float4 = 96 VGPRs.
    // greg[e*3+c] = gate_w[e][4*lane + 256*c .. +3]
    const float4* gw4 = (const float4*)gate_w;
    float4 greg[24];
#pragma unroll
    for (int e = 0; e < E; ++e)
#pragma unroll
        for (int c = 0; c < 3; ++c)
            greg[e * 3 + c] = gw4[e * D4 + c * 64 + lane];

    const float4* h4 = (const float4*)h;
    const int npairs = B >> 1;

    int p = gwave;
    if (p >= npairs) return;

    float4 cv[6];
    load_pair(cv, h4, p, lane);      // prime the pipeline

    while (true) {
        const int pn = p + nwaves;
        const bool more = (pn < npairs);   // wave-uniform branch

        float4 nv[6];
        if (more) load_pair(nv, h4, pn, lane);   // in flight during compute

        float acc0[E], acc1[E];
#pragma unroll
        for (int e = 0; e < E; ++e) { acc0[e] = 0.0f; acc1[e] = 0.0f; }

#pragma unroll
        for (int c = 0; c < 3; ++c) {
#pragma unroll
            for (int e = 0; e < E; ++e) {
                float4 g = greg[e * 3 + c];
                acc0[e] = dot4acc(cv[c],     g, acc0[e]);
                acc1[e] = dot4acc(cv[3 + c], g, acc1[e]);
            }
        }

        float va = wave_reduce8(acc0, lane) + bias;
        float vb = wave_reduce8(acc1, lane) + bias;

        // Even 8-lane groups handle row 2p, odd groups row 2p+1.
        float v = (lane & 8) ? vb : va;

        // Lanes 0..15 write both rows' logits as one contiguous 64 B chunk.
        if (lane < 16) out_logits[(size_t)p * 16 + (lane & 8) + e_lane] = v;

        // Fused top-2 within each 8-lane group. Each lane holds (v, e_lane);
        // merge sorted top-2 pairs over xor 1,2,4. Comparator matches
        // lax.top_k: strict > on value, lower expert index wins ties.
        float t0 = v;          int x0 = e_lane;
        float t1 = -INFINITY;  int x1 = E;      // sentinel
#pragma unroll
        for (int m = 1; m <= 4; m <<= 1) {
            float w0 = __shfl_xor(t0, m, 64);
            int   j0 = __shfl_xor(x0, m, 64);
            float w1 = __shfl_xor(t1, m, 64);
            int   j1 = __shfl_xor(x1, m, 64);
            // merge (t0,x0,t1,x1) with (w0,j0,w1,j1), both sorted desc
            bool aFirst = (t0 > w0) || (t0 == w0 && x0 < j0);
            float f0  = aFirst ? t0 : w0;
            int   fi0 = aFirst ? x0 : j0;
            float losT = aFirst ? w0 : t0;   // loser's first
            int   losI = aFirst ? j0 : x0;
            float winT = aFirst ? t1 : w1;   // winner's second
            int   winI = aFirst ? x1 : j1;
            bool sWin = (winT > losT) || (winT == losT && winI < losI);
            float f1  = sWin ? winT : losT;
            int   fi1 = sWin ? winI : losI;
            t0 = f0; x0 = fi0; t1 = f1; x1 = fi1;
        }

        // Lane 0 writes row 2p, lane 8 writes row 2p+1 (contiguous 16 B
        // across the two lanes for each of out_idx / out_w).
        if ((lane & 7) == 0 && lane < 16) {
            float tt = expf(t1 - t0);
            float w0_ = 1.0f / (1.0f + tt);
            float w1_ = tt * w0_;
            const int row = 2 * p + (lane >> 3);
            ((float2*)out_idx)[row] = make_float2((float)x0, (float)x1);
            ((float2*)out_w)[row]   = make_float2(w0_, w1_);
        }

        if (!more) break;
#pragma unroll
        for (int i = 0; i < 6; ++i) cv[i] = nv[i];
        p = pn;
    }
}

extern "C" void kernel_launch(void* const* d_in, const int* in_sizes, int n_in,
                              void* d_out, int out_size, void* d_ws, size_t ws_size,
                              hipStream_t stream) {
    const float* h      = (const float*)d_in[0];
    const float* gate_w = (const float*)d_in[1];
    const float* gate_b = (const float*)d_in[2];

    const int B = in_sizes[0] / D;   // 32768

    float* out        = (float*)d_out;
    float* out_idx    = out;                       // [B,2] indices as float
    float* out_w      = out + (size_t)B * 2;       // [B,2] weights
    float* out_logits = out + (size_t)B * 4;       // [B,8] logits

    router_fused_kernel<<<dim3(GRID_A), dim3(BLOCK), 0, stream>>>(
        h, gate_w, gate_b, out_idx, out_w, out_logits, B);
}